// Round 8
// baseline (107.892 us; speedup 1.0000x reference)
//
#include <hip/hip_runtime.h>

#define CC 192
#define NN 16384
#define XST 198   // staging stride (elems) = 99 dw (odd) -> conflict-free writes+reads

typedef unsigned short u16;
typedef __attribute__((ext_vector_type(4))) float f32x4;
typedef __attribute__((ext_vector_type(8))) __bf16 bf16x8;
typedef __attribute__((ext_vector_type(8))) u16 u16x8;
typedef __attribute__((ext_vector_type(4))) u16 u16x4;

union FragU { u16x8 u; bf16x8 b; };

__device__ __forceinline__ u16 f2bf(float f) {
  union { float f; unsigned u; } x; x.f = f;
  return (u16)((x.u + 0x7FFFu + ((x.u >> 16) & 1u)) >> 16);  // RNE
}
__device__ __forceinline__ float bf2f(u16 h) {
  union { unsigned u; float f; } x; x.u = ((unsigned)h) << 16;
  return x.f;
}

// K/V projection, ONE staging round: stage all 192 ch x 64 tok, then 6 MFMA
// k-steps. z=0: Sexp = exp(Wk@k+bk); z=1: Vbuf = Wv@v+bv (bf16 [b][e][n]).
__global__ __launch_bounds__(256, 2)
void kproj(const float* __restrict__ k, const float* __restrict__ v,
           const u16* __restrict__ Wb, const float* __restrict__ bk,
           const float* __restrict__ bv, u16* __restrict__ Sexp,
           u16* __restrict__ Vbuf)
{
  __shared__ __align__(16) u16 Xs[64][XST];    // 25.3 KB -> 6 blocks/CU by LDS
  const int b = blockIdx.y, pj = blockIdx.z;
  const int t0 = blockIdx.x * 64;
  const int tid = threadIdx.x;
  const int lg = (tid >> 4) & 3, lc = tid & 15;
  const int wave = tid >> 6, e0 = wave * 48;
  const int sn = tid & 63;

  const float* xb = (pj ? v : k) + (size_t)b * CC * NN;
  const u16* Wp = Wb + (pj ? 2 : 1) * 36864;
  const float* bias = pj ? bv : bk;
  u16* outp = pj ? Vbuf : Sexp;

  // ---- stage: issue all 48 channel-dword loads (deep MLP), then cvt+write ----
  f32x4 p[12];
#pragma unroll
  for (int i = 0; i < 12; ++i) {
    const float* src = xb + (size_t)(wave * 4 + i * 16) * NN + t0 + sn;
    p[i][0] = src[0]; p[i][1] = src[NN]; p[i][2] = src[2 * NN]; p[i][3] = src[3 * NN];
  }
#pragma unroll
  for (int i = 0; i < 12; ++i) {
    u16x4 pk;
    pk[0] = f2bf(p[i][0]); pk[1] = f2bf(p[i][1]);
    pk[2] = f2bf(p[i][2]); pk[3] = f2bf(p[i][3]);
    *reinterpret_cast<u16x4*>(&Xs[sn][wave * 4 + i * 16]) = pk;
  }

  // prefetch ks=0 W-frags before the barrier (hides L2 latency under the sync)
  FragU a0[3];
#pragma unroll
  for (int et = 0; et < 3; ++et)
    a0[et].u = *reinterpret_cast<const u16x8*>(&Wp[(e0 + et * 16 + lc) * 192 + lg * 8]);

  __syncthreads();

  // ---- 6 MFMA k-steps over CC=192 ----
  f32x4 acc[3][4];
#pragma unroll
  for (int et = 0; et < 3; ++et)
#pragma unroll
    for (int nt = 0; nt < 4; ++nt) acc[et][nt] = f32x4{0.f, 0.f, 0.f, 0.f};

#pragma unroll
  for (int ks = 0; ks < 6; ++ks) {
    FragU a[3], bb[4];
#pragma unroll
    for (int et = 0; et < 3; ++et)
      a[et] = (ks == 0) ? a0[et] : *(FragU*)&Wp[(e0 + et * 16 + lc) * 192 + ks * 32 + lg * 8];
#pragma unroll
    for (int nt = 0; nt < 4; ++nt)
      bb[nt].u = *reinterpret_cast<const u16x8*>(&Xs[nt * 16 + lc][ks * 32 + lg * 8]);
#pragma unroll
    for (int et = 0; et < 3; ++et)
#pragma unroll
      for (int nt = 0; nt < 4; ++nt)
        acc[et][nt] = __builtin_amdgcn_mfma_f32_16x16x32_bf16(a[et].b, bb[nt].b,
                                                             acc[et][nt], 0, 0, 0);
  }

  // ---- epilogue: bias (+exp for K), bf16 stores ----
#pragma unroll
  for (int et = 0; et < 3; ++et)
#pragma unroll
    for (int r = 0; r < 4; ++r) {
      const int e = e0 + et * 16 + lg * 4 + r;
      const float bb = bias[e];
      u16* orow = outp + (size_t)(b * 192 + e) * NN + t0;
#pragma unroll
      for (int nt = 0; nt < 4; ++nt) {
        float val = acc[et][nt][r] + bb;
        if (!pj) val = __expf(val);        // |kp| small; no max-sub needed
        orow[nt * 16 + lc] = f2bf(val);
      }
    }
}

// ctx partials: block = (128-token slab, batch); 8 waves, wave = head. No LDS.
__global__ __launch_bounds__(512, 2)
void kctx(const u16* __restrict__ Sexp, const u16* __restrict__ Vbuf,
          float* __restrict__ part)
{
  const int b = blockIdx.y, slab = blockIdx.x;
  const int tid = threadIdx.x;
  const int h = tid >> 6;
  const int lg = (tid >> 4) & 3, lc = tid & 15;
  const int n0 = slab * 128;
  const size_t basee = (size_t)b * 192 * NN;

  f32x4 cacc[2][2];
#pragma unroll
  for (int mt = 0; mt < 2; ++mt)
#pragma unroll
    for (int nt = 0; nt < 2; ++nt) cacc[mt][nt] = f32x4{0.f, 0.f, 0.f, 0.f};

#pragma unroll
  for (int ks = 0; ks < 4; ++ks) {
    const int tok = n0 + ks * 32 + lg * 8;
    FragU av[2], bs[2];
#pragma unroll
    for (int mt = 0; mt < 2; ++mt) {
      int row = h * 24 + mt * 16 + lc;   // rows >= h*24+24 feed masked outputs
      if (row > 191) row = 191;
      av[mt].u = *reinterpret_cast<const u16x8*>(&Vbuf[basee + (size_t)row * NN + tok]);
      bs[mt].u = *reinterpret_cast<const u16x8*>(&Sexp[basee + (size_t)row * NN + tok]);
    }
#pragma unroll
    for (int mt = 0; mt < 2; ++mt)
#pragma unroll
      for (int nt = 0; nt < 2; ++nt)
        cacc[mt][nt] = __builtin_amdgcn_mfma_f32_16x16x32_bf16(
            av[mt].b, bs[nt].b, cacc[mt][nt], 0, 0, 0);
  }

  float* pp = part + (((size_t)(b * 128 + slab)) * 8 + h) * 576;
#pragma unroll
  for (int mt = 0; mt < 2; ++mt)
#pragma unroll
    for (int nt = 0; nt < 2; ++nt)
#pragma unroll
      for (int r = 0; r < 4; ++r) {
        const int dv = mt * 16 + lg * 4 + r;
        const int d = nt * 16 + lc;
        if (dv < 24 && d < 24) pp[dv * 24 + d] = cacc[mt][nt][r];
      }
}

// ksum[row] = sum_n Sexp[row][n]
__global__ __launch_bounds__(256, 2)
void krow(const u16* __restrict__ Sexp, float* __restrict__ ksum)
{
  __shared__ float red[4];
  const int row = blockIdx.x;
  const int tid = threadIdx.x;
  const u16* p = Sexp + (size_t)row * NN;
  float s = 0.f;
#pragma unroll
  for (int i = 0; i < 8; ++i) {
    u16x8 vv = *reinterpret_cast<const u16x8*>(&p[(i * 256 + tid) * 8]);
#pragma unroll
    for (int j = 0; j < 8; ++j) s += bf2f(vv[j]);
  }
#pragma unroll
  for (int off = 1; off < 64; off <<= 1) s += __shfl_xor(s, off);
  if ((tid & 63) == 0) red[tid >> 6] = s;
  __syncthreads();
  if (tid == 0) ksum[row] = red[0] + red[1] + red[2] + red[3];
}

// Reduce 128 slab partials + normalize
__global__ void kr2(const float* __restrict__ part, const float* __restrict__ ksum,
                    float* __restrict__ ctx)
{
  const int idx = blockIdx.x * 256 + threadIdx.x;
  if (idx >= 4608) return;
  const int b = blockIdx.y;
  const int h = idx / 576, rem = idx % 576;
  const int d = rem % 24;
  float s = 0.f;
  const float* pp = part + (size_t)b * 128 * 4608 + idx;
#pragma unroll 8
  for (int j = 0; j < 128; ++j) s += pp[(size_t)j * 4608];
  ctx[(size_t)b * 4608 + idx] = s / ksum[b * 192 + h * 24 + d];
}

// Meff[b][o][h*24+d] = sum_dv Wo[o][h*24+dv] * ctx[b][h][dv*24+d]
__global__ void km(const float* __restrict__ Wo, const float* __restrict__ ctx,
                   u16* __restrict__ Meff)
{
  const int o = blockIdx.x, b = blockIdx.y, j = threadIdx.x;
  const int h = j / 24, d = j % 24;
  const float* Wrow = Wo + o * 192 + h * 24;
  const float* crow = ctx + (size_t)b * 4608 + h * 576 + d;
  float acc = 0.f;
#pragma unroll
  for (int dv = 0; dv < 24; ++dv) acc += Wrow[dv] * crow[dv * 24];
  Meff[(b * 192 + o) * 192 + j] = f2bf(acc);
}

// Q kernel: one-round q-proj -> SsT (same LDS buffer) -> softmax -> Meff GEMM -> out.
__global__ __launch_bounds__(256, 2)
void kq(const float* __restrict__ q, const u16* __restrict__ Wb,
        const float* __restrict__ bq, const u16* __restrict__ Meff,
        const float* __restrict__ bo, float* __restrict__ out)
{
  __shared__ __align__(16) u16 S[64][XST];     // Xs during proj, SsT after

  const int b = blockIdx.y;
  const int t0 = blockIdx.x * 64;
  const int tid = threadIdx.x;
  const int lg = (tid >> 4) & 3, lc = tid & 15;
  const int wave = tid >> 6, e0 = wave * 48;
  const int sn = tid & 63;
  const u16* Mb = Meff + b * 36864;

  // ---- stage q tile ----
  f32x4 p[12];
  const float* xb = q + (size_t)b * CC * NN;
#pragma unroll
  for (int i = 0; i < 12; ++i) {
    const float* src = xb + (size_t)(wave * 4 + i * 16) * NN + t0 + sn;
    p[i][0] = src[0]; p[i][1] = src[NN]; p[i][2] = src[2 * NN]; p[i][3] = src[3 * NN];
  }
#pragma unroll
  for (int i = 0; i < 12; ++i) {
    u16x4 pk;
    pk[0] = f2bf(p[i][0]); pk[1] = f2bf(p[i][1]);
    pk[2] = f2bf(p[i][2]); pk[3] = f2bf(p[i][3]);
    *reinterpret_cast<u16x4*>(&S[sn][wave * 4 + i * 16]) = pk;
  }
  FragU a0[3];
#pragma unroll
  for (int et = 0; et < 3; ++et)
    a0[et].u = *reinterpret_cast<const u16x8*>(&Wb[(e0 + et * 16 + lc) * 192 + lg * 8]);
  __syncthreads();

  // ---- q-projection GEMM ----
  f32x4 acc[3][4];
#pragma unroll
  for (int et = 0; et < 3; ++et)
#pragma unroll
    for (int nt = 0; nt < 4; ++nt) acc[et][nt] = f32x4{0.f, 0.f, 0.f, 0.f};
#pragma unroll
  for (int ks = 0; ks < 6; ++ks) {
    FragU a[3], bb[4];
#pragma unroll
    for (int et = 0; et < 3; ++et)
      a[et] = (ks == 0) ? a0[et] : *(FragU*)&Wb[(e0 + et * 16 + lc) * 192 + ks * 32 + lg * 8];
#pragma unroll
    for (int nt = 0; nt < 4; ++nt)
      bb[nt].u = *reinterpret_cast<const u16x8*>(&S[nt * 16 + lc][ks * 32 + lg * 8]);
#pragma unroll
    for (int et = 0; et < 3; ++et)
#pragma unroll
      for (int nt = 0; nt < 4; ++nt)
        acc[et][nt] = __builtin_amdgcn_mfma_f32_16x16x32_bf16(a[et].b, bb[nt].b,
                                                             acc[et][nt], 0, 0, 0);
  }
  __syncthreads();   // all waves done reading Xs before overwriting as SsT

  // ---- write SsT[n][e] (transposed) into the same buffer ----
#pragma unroll
  for (int et = 0; et < 3; ++et)
#pragma unroll
    for (int r = 0; r < 4; ++r) {
      const int e = e0 + et * 16 + lg * 4 + r;
      const float bias = bq[e];
#pragma unroll
      for (int nt = 0; nt < 4; ++nt)
        S[nt * 16 + lc][e] = f2bf(acc[et][nt][r] + bias);
    }
  __syncthreads();

  // ---- softmax over d (24) per (token, head), in-place ----
#pragma unroll
  for (int ii = 0; ii < 2; ++ii) {
    const int item = ii * 256 + tid;
    const int n = item & 63, h = item >> 6;
    u16* rowp = &S[n][h * 24];
    float vals[24];
    float m = -1e30f;
#pragma unroll
    for (int d = 0; d < 24; ++d) {
      vals[d] = bf2f(rowp[d]);
      m = fmaxf(m, vals[d]);
    }
    float s = 0.f;
#pragma unroll
    for (int d = 0; d < 24; ++d) { vals[d] = __expf(vals[d] - m); s += vals[d]; }
    const float inv = 1.f / s;
#pragma unroll
    for (int d = 0; d < 24; ++d) rowp[d] = f2bf(vals[d] * inv);
  }
  __syncthreads();

  // ---- output GEMM: Meff (192x192) @ SsT^T ----
#pragma unroll
  for (int et = 0; et < 3; ++et)
#pragma unroll
    for (int nt = 0; nt < 4; ++nt) acc[et][nt] = f32x4{0.f, 0.f, 0.f, 0.f};
#pragma unroll
  for (int ks = 0; ks < 6; ++ks) {
    FragU a[3], bb[4];
#pragma unroll
    for (int et = 0; et < 3; ++et)
      a[et].u = *reinterpret_cast<const u16x8*>(
          &Mb[(e0 + et * 16 + lc) * 192 + ks * 32 + lg * 8]);
#pragma unroll
    for (int nt = 0; nt < 4; ++nt)
      bb[nt].u = *reinterpret_cast<const u16x8*>(&S[nt * 16 + lc][ks * 32 + lg * 8]);
#pragma unroll
    for (int et = 0; et < 3; ++et)
#pragma unroll
      for (int nt = 0; nt < 4; ++nt)
        acc[et][nt] = __builtin_amdgcn_mfma_f32_16x16x32_bf16(a[et].b, bb[nt].b,
                                                             acc[et][nt], 0, 0, 0);
  }

#pragma unroll
  for (int et = 0; et < 3; ++et)
#pragma unroll
    for (int r = 0; r < 4; ++r) {
      const int row = e0 + et * 16 + lg * 4 + r;
      const float bias = bo[row];
#pragma unroll
      for (int nt = 0; nt < 4; ++nt)
        out[(size_t)(b * 192 + row) * NN + t0 + nt * 16 + lc] = acc[et][nt][r] + bias;
    }
}

// Convert Wq/Wk/Wv to bf16 (packed [3][192][192]).
__global__ void kz(const float* __restrict__ Wq, const float* __restrict__ Wk,
                   const float* __restrict__ Wv, u16* __restrict__ Wb)
{
  const int i = blockIdx.x * 256 + threadIdx.x;
  if (i < 110592) {
    const float* src = (i < 36864) ? Wq : (i < 73728) ? Wk : Wv;
    Wb[i] = f2bf(src[i % 36864]);
  }
}

extern "C" void kernel_launch(void* const* d_in, const int* in_sizes, int n_in,
                              void* d_out, int out_size, void* d_ws, size_t ws_size,
                              hipStream_t stream)
{
  const float* q  = (const float*)d_in[0];
  const float* k  = (const float*)d_in[1];
  const float* v  = (const float*)d_in[2];
  const float* Wq = (const float*)d_in[3];
  const float* bq = (const float*)d_in[4];
  const float* Wk = (const float*)d_in[5];
  const float* bk = (const float*)d_in[6];
  const float* Wv = (const float*)d_in[7];
  const float* bv = (const float*)d_in[8];
  const float* Wo = (const float*)d_in[9];
  const float* bo = (const float*)d_in[10];
  float* out = (float*)d_out;

  // workspace carve (256B-aligned); total ~60.4 MB
  char* w = (char*)d_ws;
  u16*   Wb   = (u16*)(w);                     // 221184 B
  u16*   Sexp = (u16*)(w + 221184);            // 25165824 B : [4][192][16384] bf16
  u16*   Vbuf = (u16*)(w + 25387008);          // 25165824 B
  float* part = (float*)(w + 50552832);        // 9437184 B : [4][128][8][576]
  float* ksum = (float*)(w + 59990016);        // 3072 B
  float* ctx  = (float*)(w + 59993088);        // 73728 B
  u16*   Meff = (u16*)(w + 60066816);          // 294912 B

  hipLaunchKernelGGL(kz, dim3(432), dim3(256), 0, stream, Wq, Wk, Wv, Wb);
  hipLaunchKernelGGL(kproj, dim3(256, 4, 2), dim3(256), 0, stream,
                     k, v, Wb, bk, bv, Sexp, Vbuf);
  hipLaunchKernelGGL(krow, dim3(768), dim3(256), 0, stream, Sexp, ksum);
  hipLaunchKernelGGL(kctx, dim3(128, 4), dim3(512), 0, stream, Sexp, Vbuf, part);
  hipLaunchKernelGGL(kr2, dim3(18, 4), dim3(256), 0, stream, part, ksum, ctx);
  hipLaunchKernelGGL(km, dim3(192, 4), dim3(192), 0, stream, Wo, ctx, Meff);
  hipLaunchKernelGGL(kq, dim3(256, 4), dim3(256), 0, stream, q, Wb, bq, Meff, bo, out);
}

// Round 9
// 103.245 us; speedup vs baseline: 1.0450x; 1.0450x over previous
//
#include <hip/hip_runtime.h>

#define CC 192
#define NN 16384
#define XST 198   // staging stride (elems) = 99 dw (odd)
#define QST 200   // kq SsT stride

typedef unsigned short u16;
typedef __attribute__((ext_vector_type(4))) float f32x4;
typedef __attribute__((ext_vector_type(8))) __bf16 bf16x8;
typedef __attribute__((ext_vector_type(8))) u16 u16x8;
typedef __attribute__((ext_vector_type(4))) u16 u16x4;

union FragU { u16x8 u; bf16x8 b; };

__device__ __forceinline__ u16 f2bf(float f) {
  union { float f; unsigned u; } x; x.f = f;
  return (u16)((x.u + 0x7FFFu + ((x.u >> 16) & 1u)) >> 16);  // RNE
}
__device__ __forceinline__ float bf2f(u16 h) {
  union { unsigned u; float f; } x; x.u = ((unsigned)h) << 16;
  return x.f;
}

// K/V projection. Staging: 12 x dwordx4 loads (4 tokens/lane, 1KB/wave-instr),
// transposed b16 LDS writes. All 18 W b128 frags hoisted to registers up front.
// z=0: Sexp = exp(Wk@k+bk); z=1: Vbuf = Wv@v+bv (bf16 [b][e][n]).
__global__ __launch_bounds__(256, 2)
void kproj(const float* __restrict__ k, const float* __restrict__ v,
           const u16* __restrict__ Wb, const float* __restrict__ bk,
           const float* __restrict__ bv, u16* __restrict__ Sexp,
           u16* __restrict__ Vbuf)
{
  __shared__ __align__(16) u16 Xs[64][XST];    // 25.3 KB
  const int b = blockIdx.y, pj = blockIdx.z;
  const int t0 = blockIdx.x * 64;
  const int tid = threadIdx.x;
  const int lg = (tid >> 4) & 3, lc = tid & 15;
  const int wave = tid >> 6, e0 = wave * 48;
  const int tg = tid & 15, chq = tid >> 4;     // token-group / channel-quad

  const float* xb = (pj ? v : k) + (size_t)b * CC * NN;
  const u16* Wp = Wb + (pj ? 2 : 1) * 36864;
  const float* bias = pj ? bv : bk;
  u16* outp = pj ? Vbuf : Sexp;

  // ---- issue all X loads (HBM, long pole) ----
  f32x4 p[12];
#pragma unroll
  for (int i = 0; i < 12; ++i)
    p[i] = *reinterpret_cast<const f32x4*>(xb + (size_t)(i * 16 + chq) * NN + t0 + tg * 4);

  // ---- issue all W-frag loads (L2/L3-hot) ----
  FragU wfr[6][3];
#pragma unroll
  for (int ks = 0; ks < 6; ++ks)
#pragma unroll
    for (int et = 0; et < 3; ++et)
      wfr[ks][et].u = *reinterpret_cast<const u16x8*>(
          &Wp[(e0 + et * 16 + lc) * 192 + ks * 32 + lg * 8]);

  // ---- cvt + transposed LDS writes ----
#pragma unroll
  for (int i = 0; i < 12; ++i) {
    const int ch = i * 16 + chq;
    Xs[tg * 4 + 0][ch] = f2bf(p[i][0]);
    Xs[tg * 4 + 1][ch] = f2bf(p[i][1]);
    Xs[tg * 4 + 2][ch] = f2bf(p[i][2]);
    Xs[tg * 4 + 3][ch] = f2bf(p[i][3]);
  }
  __syncthreads();

  // ---- 6 MFMA k-steps, zero in-loop global loads ----
  f32x4 acc[3][4];
#pragma unroll
  for (int et = 0; et < 3; ++et)
#pragma unroll
    for (int nt = 0; nt < 4; ++nt) acc[et][nt] = f32x4{0.f, 0.f, 0.f, 0.f};

#pragma unroll
  for (int ks = 0; ks < 6; ++ks) {
    FragU bb[4];
#pragma unroll
    for (int nt = 0; nt < 4; ++nt)
      bb[nt].u = *reinterpret_cast<const u16x8*>(&Xs[nt * 16 + lc][ks * 32 + lg * 8]);
#pragma unroll
    for (int et = 0; et < 3; ++et)
#pragma unroll
      for (int nt = 0; nt < 4; ++nt)
        acc[et][nt] = __builtin_amdgcn_mfma_f32_16x16x32_bf16(wfr[ks][et].b, bb[nt].b,
                                                             acc[et][nt], 0, 0, 0);
  }

  // ---- epilogue: bias (+exp for K), bf16 stores ----
#pragma unroll
  for (int et = 0; et < 3; ++et)
#pragma unroll
    for (int r = 0; r < 4; ++r) {
      const int e = e0 + et * 16 + lg * 4 + r;
      const float bb = bias[e];
      u16* orow = outp + (size_t)(b * 192 + e) * NN + t0;
#pragma unroll
      for (int nt = 0; nt < 4; ++nt) {
        float val = acc[et][nt][r] + bb;
        if (!pj) val = __expf(val);        // |kp| small; no max-sub needed
        orow[nt * 16 + lc] = f2bf(val);
      }
    }
}

// ctx partials: block = (128-token slab, batch); 8 waves, wave = head. No LDS.
__global__ __launch_bounds__(512, 2)
void kctx(const u16* __restrict__ Sexp, const u16* __restrict__ Vbuf,
          float* __restrict__ part)
{
  const int b = blockIdx.y, slab = blockIdx.x;
  const int tid = threadIdx.x;
  const int h = tid >> 6;
  const int lg = (tid >> 4) & 3, lc = tid & 15;
  const int n0 = slab * 128;
  const size_t basee = (size_t)b * 192 * NN;

  f32x4 cacc[2][2];
#pragma unroll
  for (int mt = 0; mt < 2; ++mt)
#pragma unroll
    for (int nt = 0; nt < 2; ++nt) cacc[mt][nt] = f32x4{0.f, 0.f, 0.f, 0.f};

#pragma unroll
  for (int ks = 0; ks < 4; ++ks) {
    const int tok = n0 + ks * 32 + lg * 8;
    FragU av[2], bs[2];
#pragma unroll
    for (int mt = 0; mt < 2; ++mt) {
      int row = h * 24 + mt * 16 + lc;   // rows >= h*24+24 feed masked outputs
      if (row > 191) row = 191;
      av[mt].u = *reinterpret_cast<const u16x8*>(&Vbuf[basee + (size_t)row * NN + tok]);
      bs[mt].u = *reinterpret_cast<const u16x8*>(&Sexp[basee + (size_t)row * NN + tok]);
    }
#pragma unroll
    for (int mt = 0; mt < 2; ++mt)
#pragma unroll
      for (int nt = 0; nt < 2; ++nt)
        cacc[mt][nt] = __builtin_amdgcn_mfma_f32_16x16x32_bf16(
            av[mt].b, bs[nt].b, cacc[mt][nt], 0, 0, 0);
  }

  float* pp = part + (((size_t)(b * 128 + slab)) * 8 + h) * 576;
#pragma unroll
  for (int mt = 0; mt < 2; ++mt)
#pragma unroll
    for (int nt = 0; nt < 2; ++nt)
#pragma unroll
      for (int r = 0; r < 4; ++r) {
        const int dv = mt * 16 + lg * 4 + r;
        const int d = nt * 16 + lc;
        if (dv < 24 && d < 24) pp[dv * 24 + d] = cacc[mt][nt][r];
      }
}

// ksum[row] = sum_n Sexp[row][n]
__global__ __launch_bounds__(256, 2)
void krow(const u16* __restrict__ Sexp, float* __restrict__ ksum)
{
  __shared__ float red[4];
  const int row = blockIdx.x;
  const int tid = threadIdx.x;
  const u16* p = Sexp + (size_t)row * NN;
  float s = 0.f;
#pragma unroll
  for (int i = 0; i < 8; ++i) {
    u16x8 vv = *reinterpret_cast<const u16x8*>(&p[(i * 256 + tid) * 8]);
#pragma unroll
    for (int j = 0; j < 8; ++j) s += bf2f(vv[j]);
  }
#pragma unroll
  for (int off = 1; off < 64; off <<= 1) s += __shfl_xor(s, off);
  if ((tid & 63) == 0) red[tid >> 6] = s;
  __syncthreads();
  if (tid == 0) ksum[row] = red[0] + red[1] + red[2] + red[3];
}

// Reduce 128 slab partials + normalize
__global__ void kr2(const float* __restrict__ part, const float* __restrict__ ksum,
                    float* __restrict__ ctx)
{
  const int idx = blockIdx.x * 256 + threadIdx.x;
  if (idx >= 4608) return;
  const int b = blockIdx.y;
  const int h = idx / 576, rem = idx % 576;
  const int d = rem % 24;
  float s = 0.f;
  const float* pp = part + (size_t)b * 128 * 4608 + idx;
#pragma unroll 8
  for (int j = 0; j < 128; ++j) s += pp[(size_t)j * 4608];
  ctx[(size_t)b * 4608 + idx] = s / ksum[b * 192 + h * 24 + d];
}

// Meff[b][o][h*24+d] = sum_dv Wo[o][h*24+dv] * ctx[b][h][dv*24+d]
__global__ void km(const float* __restrict__ Wo, const float* __restrict__ ctx,
                   u16* __restrict__ Meff)
{
  const int o = blockIdx.x, b = blockIdx.y, j = threadIdx.x;
  const int h = j / 24, d = j % 24;
  const float* Wrow = Wo + o * 192 + h * 24;
  const float* crow = ctx + (size_t)b * 4608 + h * 576 + d;
  float acc = 0.f;
#pragma unroll
  for (int dv = 0; dv < 24; ++dv) acc += Wrow[dv] * crow[dv * 24];
  Meff[(b * 192 + o) * 192 + j] = f2bf(acc);
}

// Q kernel: wide-load staging -> q-proj GEMM -> SsT -> softmax -> Meff GEMM -> out.
__global__ __launch_bounds__(256, 2)
void kq(const float* __restrict__ q, const u16* __restrict__ Wb,
        const float* __restrict__ bq, const u16* __restrict__ Meff,
        const float* __restrict__ bo, float* __restrict__ out)
{
  __shared__ __align__(16) u16 Xs[64][XST];    // 25.3 KB
  __shared__ __align__(16) u16 SsT[64][QST];   // 25.6 KB

  const int b = blockIdx.y;
  const int t0 = blockIdx.x * 64;
  const int tid = threadIdx.x;
  const int lg = (tid >> 4) & 3, lc = tid & 15;
  const int wave = tid >> 6, e0 = wave * 48;
  const int tg = tid & 15, chq = tid >> 4;
  const u16* Mb = Meff + b * 36864;

  // ---- stage q tile: wide loads + hoisted W frags ----
  f32x4 p[12];
  const float* xb = q + (size_t)b * CC * NN;
#pragma unroll
  for (int i = 0; i < 12; ++i)
    p[i] = *reinterpret_cast<const f32x4*>(xb + (size_t)(i * 16 + chq) * NN + t0 + tg * 4);

  FragU wfr[6][3];
#pragma unroll
  for (int ks = 0; ks < 6; ++ks)
#pragma unroll
    for (int et = 0; et < 3; ++et)
      wfr[ks][et].u = *reinterpret_cast<const u16x8*>(
          &Wb[(e0 + et * 16 + lc) * 192 + ks * 32 + lg * 8]);

#pragma unroll
  for (int i = 0; i < 12; ++i) {
    const int ch = i * 16 + chq;
    Xs[tg * 4 + 0][ch] = f2bf(p[i][0]);
    Xs[tg * 4 + 1][ch] = f2bf(p[i][1]);
    Xs[tg * 4 + 2][ch] = f2bf(p[i][2]);
    Xs[tg * 4 + 3][ch] = f2bf(p[i][3]);
  }
  __syncthreads();

  // ---- q-projection GEMM ----
  f32x4 acc[3][4];
#pragma unroll
  for (int et = 0; et < 3; ++et)
#pragma unroll
    for (int nt = 0; nt < 4; ++nt) acc[et][nt] = f32x4{0.f, 0.f, 0.f, 0.f};
#pragma unroll
  for (int ks = 0; ks < 6; ++ks) {
    FragU bb[4];
#pragma unroll
    for (int nt = 0; nt < 4; ++nt)
      bb[nt].u = *reinterpret_cast<const u16x8*>(&Xs[nt * 16 + lc][ks * 32 + lg * 8]);
#pragma unroll
    for (int et = 0; et < 3; ++et)
#pragma unroll
      for (int nt = 0; nt < 4; ++nt)
        acc[et][nt] = __builtin_amdgcn_mfma_f32_16x16x32_bf16(wfr[ks][et].b, bb[nt].b,
                                                             acc[et][nt], 0, 0, 0);
  }

  // ---- write SsT[n][e] (transposed) + bias ----
#pragma unroll
  for (int et = 0; et < 3; ++et)
#pragma unroll
    for (int r = 0; r < 4; ++r) {
      const int e = e0 + et * 16 + lg * 4 + r;
      const float bias = bq[e];
#pragma unroll
      for (int nt = 0; nt < 4; ++nt)
        SsT[nt * 16 + lc][e] = f2bf(acc[et][nt][r] + bias);
    }
  __syncthreads();

  // ---- softmax over d (24) per (token, head), in-place ----
#pragma unroll
  for (int ii = 0; ii < 2; ++ii) {
    const int item = ii * 256 + tid;
    const int n = item & 63, h = item >> 6;
    u16* rowp = &SsT[n][h * 24];
    float vals[24];
    float m = -1e30f;
#pragma unroll
    for (int d = 0; d < 24; ++d) {
      vals[d] = bf2f(rowp[d]);
      m = fmaxf(m, vals[d]);
    }
    float s = 0.f;
#pragma unroll
    for (int d = 0; d < 24; ++d) { vals[d] = __expf(vals[d] - m); s += vals[d]; }
    const float inv = 1.f / s;
#pragma unroll
    for (int d = 0; d < 24; ++d) rowp[d] = f2bf(vals[d] * inv);
  }
  __syncthreads();

  // ---- output GEMM: Meff (192x192) @ SsT^T ----
#pragma unroll
  for (int et = 0; et < 3; ++et)
#pragma unroll
    for (int nt = 0; nt < 4; ++nt) acc[et][nt] = f32x4{0.f, 0.f, 0.f, 0.f};
#pragma unroll
  for (int ks = 0; ks < 6; ++ks) {
    FragU a[3], bb[4];
#pragma unroll
    for (int et = 0; et < 3; ++et)
      a[et].u = *reinterpret_cast<const u16x8*>(
          &Mb[(e0 + et * 16 + lc) * 192 + ks * 32 + lg * 8]);
#pragma unroll
    for (int nt = 0; nt < 4; ++nt)
      bb[nt].u = *reinterpret_cast<const u16x8*>(&SsT[nt * 16 + lc][ks * 32 + lg * 8]);
#pragma unroll
    for (int et = 0; et < 3; ++et)
#pragma unroll
      for (int nt = 0; nt < 4; ++nt)
        acc[et][nt] = __builtin_amdgcn_mfma_f32_16x16x32_bf16(a[et].b, bb[nt].b,
                                                             acc[et][nt], 0, 0, 0);
  }

#pragma unroll
  for (int et = 0; et < 3; ++et)
#pragma unroll
    for (int r = 0; r < 4; ++r) {
      const int row = e0 + et * 16 + lg * 4 + r;
      const float bias = bo[row];
#pragma unroll
      for (int nt = 0; nt < 4; ++nt)
        out[(size_t)(b * 192 + row) * NN + t0 + nt * 16 + lc] = acc[et][nt][r] + bias;
    }
}

// Convert Wq/Wk/Wv to bf16 (packed [3][192][192]).
__global__ void kz(const float* __restrict__ Wq, const float* __restrict__ Wk,
                   const float* __restrict__ Wv, u16* __restrict__ Wb)
{
  const int i = blockIdx.x * 256 + threadIdx.x;
  if (i < 110592) {
    const float* src = (i < 36864) ? Wq : (i < 73728) ? Wk : Wv;
    Wb[i] = f2bf(src[i % 36864]);
  }
}

extern "C" void kernel_launch(void* const* d_in, const int* in_sizes, int n_in,
                              void* d_out, int out_size, void* d_ws, size_t ws_size,
                              hipStream_t stream)
{
  const float* q  = (const float*)d_in[0];
  const float* k  = (const float*)d_in[1];
  const float* v  = (const float*)d_in[2];
  const float* Wq = (const float*)d_in[3];
  const float* bq = (const float*)d_in[4];
  const float* Wk = (const float*)d_in[5];
  const float* bk = (const float*)d_in[6];
  const float* Wv = (const float*)d_in[7];
  const float* bv = (const float*)d_in[8];
  const float* Wo = (const float*)d_in[9];
  const float* bo = (const float*)d_in[10];
  float* out = (float*)d_out;

  // workspace carve (256B-aligned); total ~60.4 MB
  char* w = (char*)d_ws;
  u16*   Wb   = (u16*)(w);                     // 221184 B
  u16*   Sexp = (u16*)(w + 221184);            // 25165824 B : [4][192][16384] bf16
  u16*   Vbuf = (u16*)(w + 25387008);          // 25165824 B
  float* part = (float*)(w + 50552832);        // 9437184 B : [4][128][8][576]
  float* ksum = (float*)(w + 59990016);        // 3072 B
  float* ctx  = (float*)(w + 59993088);        // 73728 B
  u16*   Meff = (u16*)(w + 60066816);          // 294912 B

  hipLaunchKernelGGL(kz, dim3(432), dim3(256), 0, stream, Wq, Wk, Wv, Wb);
  hipLaunchKernelGGL(kproj, dim3(256, 4, 2), dim3(256), 0, stream,
                     k, v, Wb, bk, bv, Sexp, Vbuf);
  hipLaunchKernelGGL(krow, dim3(768), dim3(256), 0, stream, Sexp, ksum);
  hipLaunchKernelGGL(kctx, dim3(128, 4), dim3(512), 0, stream, Sexp, Vbuf, part);
  hipLaunchKernelGGL(kr2, dim3(18, 4), dim3(256), 0, stream, part, ksum, ctx);
  hipLaunchKernelGGL(km, dim3(192, 4), dim3(192), 0, stream, Wo, ctx, Meff);
  hipLaunchKernelGGL(kq, dim3(256, 4), dim3(256), 0, stream, q, Wb, bq, Meff, bo, out);
}